// Round 4
// baseline (317.425 us; speedup 1.0000x reference)
//
#include <hip/hip_runtime.h>

// Problem constants
#define B_  16
#define T_  12
#define N_  1000
#define F_  64
#define KC  3
#define O_  64
#define NP  1024            // padded N (both i and j dims)
#define KP  (KC * NP)       // 3072 combined contraction length per b
#define CC  (T_ * O_)       // 768 output columns per b

typedef __bf16 bf16x8 __attribute__((ext_vector_type(8)));
typedef float  f32x4  __attribute__((ext_vector_type(4)));

__device__ __forceinline__ unsigned short f2bf(float f) {
  __bf16 h = (__bf16)f;                      // RNE convert
  return __builtin_bit_cast(unsigned short, h);
}

// async global->LDS, 16B per lane. LDS dest = wave-uniform base + lane*16.
__device__ __forceinline__ void gl_lds16(const void* g, void* l) {
  __builtin_amdgcn_global_load_lds(
      (const __attribute__((address_space(1))) unsigned int*)g,
      (__attribute__((address_space(3))) unsigned int*)l,
      16, 0, 0);
}

// ---------------------------------------------------------------------------
// Fused stage 1 + stage 2 (data-independent -> one dispatch, block-parallel).
// Even blocks: ASt[b][ip][k][jp] = bf16(cheb[k,j,i]*SAtt[b,j,i])  (512 blocks)
// Odd  blocks: Yt[b][t][o][k][jp] = bf16(sum_f x[b,t,j,f]*Theta[k,f,o]) (512)
// Interleaved even/odd so both kinds co-reside per CU (2 blocks/CU at 62KB).
// Bodies are verbatim from the round-3 kernels; only block-id decode changed.
// ---------------------------------------------------------------------------
struct __align__(16) SmemAs {
  unsigned short prod[KC][64][66];            // 25.3 KB
};
struct __align__(16) SmemY {
  unsigned short thl[KC][64][72];             // Theta^T [k][o][f]
  unsigned short xl[128][72];                 // x tile [j][f]
  unsigned short ot[64][136];                 // out tile [o][j]
};                                            // 62 KB
union __align__(16) SmemU { SmemAs a; SmemY y; };

__global__ __launch_bounds__(256) void k_build_fused(
    const float* __restrict__ SAtt, const float* __restrict__ cheb,
    const float* __restrict__ x,    const float* __restrict__ Theta,
    unsigned short* __restrict__ ASt, unsigned short* __restrict__ Yt) {
  __shared__ SmemU sm;
  const int tid = threadIdx.x;

  if ((blockIdx.x & 1) == 0) {
    // ---------------- build_as body (b-batched 8x) ----------------
    const int abid = blockIdx.x >> 1;         // 0..511
    const int ib = (abid & 15) * 64;
    const int jb = ((abid >> 4) & 15) * 64;
    const int bgrp = abid >> 8;               // 0..1
    auto& prod = sm.a.prod;

    const int ii4 = (tid & 15) * 4, jr = tid >> 4;
    const int gi = ib + ii4;                  // N_%4==0: f4 never straddles
    const bool iok = gi < N_;

    // preload cheb tile into registers: 4 passes x 3 k = 48 VGPR
    float4 ch[4][KC];
    int gjc[4];
    bool okm[4];
#pragma unroll
    for (int p = 0; p < 4; ++p) {
      const int gj = jb + p * 16 + jr;
      gjc[p] = gj < N_ ? gj : N_ - 1;
      okm[p] = iok && (gj < N_);
#pragma unroll
      for (int k = 0; k < KC; ++k) {
        ch[p][k] = make_float4(0.f, 0.f, 0.f, 0.f);
        if (iok)
          ch[p][k] = *(const float4*)&cheb[((size_t)k * N_ + gjc[p]) * N_ + gi];
      }
    }

    const int j8 = (tid & 7) * 8, i0 = tid >> 3;

    for (int bb = 0; bb < 8; ++bb) {
      const int b = bgrp * 8 + bb;
      const float* sb = SAtt + (size_t)b * N_ * N_;
      if (bb) __syncthreads();    // protect prod from prior transpose readers
#pragma unroll
      for (int p = 0; p < 4; ++p) {
        const int jj = p * 16 + jr;
        float4 s4 = make_float4(0.f, 0.f, 0.f, 0.f);
        if (iok) s4 = *(const float4*)&sb[(size_t)gjc[p] * N_ + gi];
#pragma unroll
        for (int k = 0; k < KC; ++k) {
          ushort2 lo, hi;
          lo.x = okm[p] ? f2bf(ch[p][k].x * s4.x) : (unsigned short)0;
          lo.y = okm[p] ? f2bf(ch[p][k].y * s4.y) : (unsigned short)0;
          hi.x = okm[p] ? f2bf(ch[p][k].z * s4.z) : (unsigned short)0;
          hi.y = okm[p] ? f2bf(ch[p][k].w * s4.w) : (unsigned short)0;
          *(ushort2*)&prod[k][jj][ii4]     = lo;
          *(ushort2*)&prod[k][jj][ii4 + 2] = hi;
        }
      }
      __syncthreads();
#pragma unroll
      for (int pp = 0; pp < 2; ++pp) {
        const int iw = pp * 32 + i0;
#pragma unroll
        for (int k = 0; k < KC; ++k) {
          unsigned short v[8];
#pragma unroll
          for (int m = 0; m < 8; ++m) v[m] = prod[k][j8 + m][iw];
          *(uint4*)&ASt[((size_t)(b * NP + ib + iw) * KC + k) * NP + jb + j8] =
              *(uint4*)v;
        }
      }
    }
  } else {
    // ---------------- build_y body (t-batched 3x) ----------------
    const int ybid = blockIdx.x >> 1;         // 0..511
    const int jb = (ybid & 7) * 128;
    const int by = (ybid >> 3) & 15;          // b
    const int tgrp = ybid >> 7;               // 0..3
    auto& thl = sm.y.thl;
    auto& xl  = sm.y.xl;
    auto& ot  = sm.y.ot;

    // Theta -> thl (transposed): float4 loads along o, scalar LDS writes
#pragma unroll
    for (int it = 0; it < 12; ++it) {
      const int e = (tid + it * 256) * 4;     // element index, mult of 4
      const int k = e >> 12, f = (e >> 6) & 63, o0 = e & 63;
      const float4 v = *(const float4*)&Theta[e];
      thl[k][o0 + 0][f] = f2bf(v.x);
      thl[k][o0 + 1][f] = f2bf(v.y);
      thl[k][o0 + 2][f] = f2bf(v.z);
      thl[k][o0 + 3][f] = f2bf(v.w);
    }

    const int w = tid >> 6, l = tid & 63, quad = l >> 4, lr = l & 15;
    const int o16 = tid >> 4, j8v = (tid & 15) * 8;

    for (int tt = 0; tt < 3; ++tt) {
      const int bt = by * T_ + tgrp * 3 + tt;
      const float* xrow = x + ((size_t)bt * N_ + jb) * F_;
#pragma unroll
      for (int p = 0; p < 8; ++p) {
        const int i4 = tid + p * 256;          // float4 index, 0..2047
        const int fl = i4 * 4, j = fl >> 6, f = fl & 63;
        float4 v;
        if (jb + j < N_) v = ((const float4*)xrow)[i4];
        else             v = make_float4(0.f, 0.f, 0.f, 0.f);
        ushort4 u;
        u.x = f2bf(v.x); u.y = f2bf(v.y); u.z = f2bf(v.z); u.w = f2bf(v.w);
        *(ushort4*)&xl[j][f] = u;
      }
      __syncthreads();

#pragma unroll
      for (int k = 0; k < KC; ++k) {
        f32x4 acc[4][2];
#pragma unroll
        for (int mi = 0; mi < 4; ++mi)
#pragma unroll
          for (int ni = 0; ni < 2; ++ni)
            acc[mi][ni] = (f32x4){0.f, 0.f, 0.f, 0.f};
#pragma unroll
        for (int ks = 0; ks < 2; ++ks) {
          const int fo = ks * 32 + quad * 8;
          bf16x8 a[4], bb[2];
#pragma unroll
          for (int mi = 0; mi < 4; ++mi)
            a[mi] = *(const bf16x8*)&thl[k][mi * 16 + lr][fo];
#pragma unroll
          for (int ni = 0; ni < 2; ++ni)
            bb[ni] = *(const bf16x8*)&xl[w * 32 + ni * 16 + lr][fo];
#pragma unroll
          for (int mi = 0; mi < 4; ++mi)
#pragma unroll
            for (int ni = 0; ni < 2; ++ni)
              acc[mi][ni] = __builtin_amdgcn_mfma_f32_16x16x32_bf16(
                  a[mi], bb[ni], acc[mi][ni], 0, 0, 0);
        }
        __syncthreads();                      // protect ot from prior readers
#pragma unroll
        for (int mi = 0; mi < 4; ++mi)
#pragma unroll
          for (int ni = 0; ni < 2; ++ni)
#pragma unroll
            for (int r = 0; r < 4; ++r)
              ot[mi * 16 + quad * 4 + r][w * 32 + ni * 16 + lr] =
                  f2bf(acc[mi][ni][r]);
        __syncthreads();
        // coalesced stores: 16 lanes x 16B = 256B contiguous per o-row
#pragma unroll
        for (int oo = 0; oo < 4; ++oo) {
          const int o = oo * 16 + o16;
          const uint4 v = *(const uint4*)&ot[o][j8v];
          *(uint4*)&Yt[((size_t)(bt * O_ + o) * KC + k) * NP + jb + j8v] = v;
        }
      }
    }
  }
}

// ---------------------------------------------------------------------------
// Stage 3: per-b GEMM  C[i,c] = sum_{K'} ASt[b][i][K'] * Yt[b][c][K'],
// M=1024(i), N=768(c), K=3072. 128x128 tile, 4 waves x (64x64), 16x16x32 bf16
// MFMA, BK=64, global_load_lds width-16. XOR chunk swizzle kills the 16-way
// LDS bank conflict of the 128B row stride. XCD-aware block swizzle (2 b/XCD).
// (round-0 verified version, ~120 us — FROZEN this round)
// ---------------------------------------------------------------------------
__global__ __launch_bounds__(256, 2) void k_gemm(
    const unsigned short* __restrict__ ASt, const unsigned short* __restrict__ Yt,
    float* __restrict__ out) {
  __shared__ unsigned short Al[128 * 64];   // [row][K-chunk swizzled], 16 KB
  __shared__ unsigned short Bl[128 * 64];
  const int tid = threadIdx.x;
  // block swizzle: bid%8 -> XCD (HW round-robin heuristic); 2 b's per XCD
  const int bid = blockIdx.x;
  const int xcd = bid & 7, s = bid >> 3;          // s = 0..95
  const int b = xcd * 2 + (s / 48);
  const int r48 = s % 48;
  const int ib = (r48 / 6) * 128, cb = (r48 % 6) * 128;

  const unsigned short* Abase = ASt + ((size_t)b * NP + ib) * KP;
  const unsigned short* Bbase = Yt + ((size_t)b * CC + cb) * KP;
  const int w = tid >> 6, l = tid & 63, quad = l >> 4, lr = l & 15;
  const int wr = w & 1, wc = w >> 1;
  const int lrow = l >> 3, lchunk = l & 7;
  const int src_chunk = lchunk ^ lrow;            // XOR swizzle (staging side)
  const int p0 = quad ^ (lr & 7);                 // phys chunk, ks=0 (read side)

  f32x4 acc[4][4];
#pragma unroll
  for (int mi = 0; mi < 4; ++mi)
#pragma unroll
    for (int ci = 0; ci < 4; ++ci)
      acc[mi][ci] = (f32x4){0.f, 0.f, 0.f, 0.f};

  for (int kt = 0; kt < KP / 64; ++kt) {
    __syncthreads();                        // protect LDS from prior readers
    const int k0 = kt * 64;
#pragma unroll
    for (int s4 = 0; s4 < 4; ++s4) {
      const int row = w * 32 + s4 * 8;      // wave-uniform LDS base row
      gl_lds16(Abase + (size_t)(row + lrow) * KP + k0 + src_chunk * 8,
               &Al[row * 64]);
      gl_lds16(Bbase + (size_t)(row + lrow) * KP + k0 + src_chunk * 8,
               &Bl[row * 64]);
    }
    __syncthreads();                        // drains vmcnt(0) -> LDS valid
#pragma unroll
    for (int ks = 0; ks < 2; ++ks) {
      const int pc = (p0 ^ (ks * 4)) * 8;   // swizzled chunk -> ushort offset
      bf16x8 a[4], bb[4];
#pragma unroll
      for (int mi = 0; mi < 4; ++mi)
        a[mi] = *(const bf16x8*)&Al[(wr * 64 + mi * 16 + lr) * 64 + pc];
#pragma unroll
      for (int ci = 0; ci < 4; ++ci)
        bb[ci] = *(const bf16x8*)&Bl[(wc * 64 + ci * 16 + lr) * 64 + pc];
#pragma unroll
      for (int mi = 0; mi < 4; ++mi)
#pragma unroll
        for (int ci = 0; ci < 4; ++ci)
          acc[mi][ci] = __builtin_amdgcn_mfma_f32_16x16x32_bf16(
              a[mi], bb[ci], acc[mi][ci], 0, 0, 0);
    }
  }

  // epilogue: C/D layout col=lane&15 (->c), row=quad*4+reg (->i). ReLU fused.
#pragma unroll
  for (int mi = 0; mi < 4; ++mi) {
    const int i = ib + wr * 64 + mi * 16 + quad * 4;
#pragma unroll
    for (int ci = 0; ci < 4; ++ci) {
      const int c = cb + wc * 64 + ci * 16 + lr;
      const int t = c >> 6, o = c & 63;      // 16-aligned tile: single t
#pragma unroll
      for (int r = 0; r < 4; ++r) {
        if (i + r < N_) {
          const float v = acc[mi][ci][r];
          out[((size_t)(b * T_ + t) * N_ + (i + r)) * O_ + o] = v > 0.f ? v : 0.f;
        }
      }
    }
  }
}

// ---------------------------------------------------------------------------
extern "C" void kernel_launch(void* const* d_in, const int* in_sizes, int n_in,
                              void* d_out, int out_size, void* d_ws, size_t ws_size,
                              hipStream_t stream) {
  const float* x     = (const float*)d_in[0];
  const float* SAtt  = (const float*)d_in[1];
  const float* cheb  = (const float*)d_in[2];
  const float* Theta = (const float*)d_in[3];
  float* out = (float*)d_out;

  unsigned short* ASt = (unsigned short*)d_ws;                 // 100.7 MB
  unsigned short* Yt  = ASt + (size_t)B_ * NP * KC * NP;       //  75.5 MB

  k_build_fused<<<1024, 256, 0, stream>>>(SAtt, cheb, x, Theta, ASt, Yt);
  k_gemm<<<768, 256, 0, stream>>>(ASt, Yt, out);
}